// Round 1
// baseline (143.849 us; speedup 1.0000x reference)
//
#include <hip/hip_runtime.h>
#include <math.h>

#define S_LEN  4096
#define NCH    64
#define TILE_S 128
#define RPT    16          // s-rows per thread
#define TY     8           // blockDim.y -> 512 threads = 8 waves
#define HALO_L 31
#define STAGE  (TILE_S + 61)   // 189 staged rows

// weights: w6 at [0..61], w3 at [62..93], w1 at [94..105]
__device__ float g_wt[112];

// ---------------------------------------------------------------------------
// Setup: replicate pywt/gaus1 integrated-wavelet filter construction exactly.
// numpy: x = linspace(-5,5,1024); step = x[1]-x[0];
//        psi = -2x e^{-x^2}/(pi/2)^{1/4}; int_psi = cumsum(psi)*step;
//        j = (arange(10a+1)/(a*step)).astype(int64); filt = int_psi[j] (f32)
// Fused filter (conv + diff + trim folded): w_a[t] = -sqrt(a)*(k[t-1]-k[t]),
// t = 0..Lf  (Lf = 10a+1 taps, k[-1]=k[Lf]=0).
// The j index computation is replicated in identical fp64 ops so floor
// decisions match numpy bit-exactly.
// ---------------------------------------------------------------------------
__global__ void cwt_setup() {
  __shared__ double ip[1024];
  __shared__ double tsum[64];
  const int t = threadIdx.x;                 // 64 threads
  const double delta = 10.0 / 1023.0;
  const double step  = (-5.0 + delta) + 5.0; // == numpy x[1]-x[0]
  const double cnorm = pow(3.141592653589793 * 0.5, 0.25);

  double local[16];
  double s = 0.0;
  #pragma unroll
  for (int i = 0; i < 16; ++i) {
    const int idx = t * 16 + i;
    const double p  = (double)idx * delta;
    const double xi = (idx == 1023) ? 5.0 : (p - 5.0); // linspace forces endpoint
    const double psi = (-2.0 * xi) * exp(-(xi * xi)) / cnorm;
    s += psi;
    local[i] = s;
  }
  tsum[t] = s;
  __syncthreads();
  double off = 0.0;
  for (int k = 0; k < t; ++k) off += tsum[k];
  #pragma unroll
  for (int i = 0; i < 16; ++i) ip[t * 16 + i] = (local[i] + off) * step;
  __syncthreads();

  const int as_[3]  = {6, 3, 1};
  const int lf_[3]  = {61, 31, 11};   // filter tap counts (10a+1)
  const int ofs_[3] = {0, 62, 94};
  for (int si = 0; si < 3; ++si) {
    const double denom = (double)as_[si] * step;
    const float  sqa   = (float)sqrt((double)as_[si]);
    const int    lf    = lf_[si];
    for (int tt = t; tt <= lf; tt += 64) {
      float km1 = 0.f, kt = 0.f;
      if (tt >= 1)      km1 = (float)ip[(long)(((double)(tt - 1)) / denom)];
      if (tt <= lf - 1) kt  = (float)ip[(long)(((double)tt) / denom)];
      g_wt[ofs_[si] + tt] = -sqa * (km1 - kt);
    }
  }
}

// ---------------------------------------------------------------------------
// Main: out[b][si][s][c] = sum_t w[t] * x[b][s+off+t][c], zero-padded in s.
// Unified window base = s-31:  w6 at u=t (0..61), w3 at u=t+15, w1 at u=t+25.
// Block: 64 channels x TY rows-of-threads; each thread does RPT s-positions.
// ---------------------------------------------------------------------------
__global__ __launch_bounds__(512)
void cwt_main(const float* __restrict__ x, float* __restrict__ out) {
  __shared__ float lds[STAGE * NCH];
  const int c   = threadIdx.x;        // 0..63 (one wave per ty)
  const int ty  = threadIdx.y;        // 0..7
  const int tid = ty * 64 + c;
  const int b   = blockIdx.y;
  const int s0  = blockIdx.x * TILE_S;
  const float* xb = x + (size_t)b * S_LEN * NCH;
  const int row0 = s0 - HALO_L;

  // stage rows [s0-31 .. s0+127+30] as float4, zero-fill out of range
  for (int idx = tid; idx < STAGE * 16; idx += TY * 64) {
    const int r = idx >> 4, q = idx & 15;
    const int row = row0 + r;
    float4 v = make_float4(0.f, 0.f, 0.f, 0.f);
    if (row >= 0 && row < S_LEN)
      v = *(const float4*)(xb + ((size_t)row * NCH + (q << 2)));
    *(float4*)(&lds[r * NCH + (q << 2)]) = v;
  }
  __syncthreads();

  const int base = ty * RPT;
  float win[61 + RPT];                       // 77 regs: rows base..base+76
  #pragma unroll
  for (int u = 0; u < 61 + RPT; ++u) win[u] = lds[(base + u) * NCH + c];

  float* outb = out + (size_t)b * 3 * S_LEN * NCH;
  const int srow = s0 + base;

  // ---- scale 6 (out index 2), taps g_wt[0..61], window u = t ----
  {
    float acc[RPT];
    #pragma unroll
    for (int r = 0; r < RPT; ++r) acc[r] = 0.f;
    #pragma unroll
    for (int t = 0; t < 62; ++t) {
      const float wv = g_wt[t];              // uniform -> s_load
      #pragma unroll
      for (int r = 0; r < RPT; ++r) acc[r] += wv * win[t + r];
    }
    float* o = outb + ((size_t)(2 * S_LEN + srow)) * NCH + c;
    #pragma unroll
    for (int r = 0; r < RPT; ++r) o[(size_t)r * NCH] = acc[r];
  }
  // ---- scale 3 (out index 1), taps g_wt[62..93], window u = t+15 ----
  {
    float acc[RPT];
    #pragma unroll
    for (int r = 0; r < RPT; ++r) acc[r] = 0.f;
    #pragma unroll
    for (int t = 0; t < 32; ++t) {
      const float wv = g_wt[62 + t];
      #pragma unroll
      for (int r = 0; r < RPT; ++r) acc[r] += wv * win[t + 15 + r];
    }
    float* o = outb + ((size_t)(1 * S_LEN + srow)) * NCH + c;
    #pragma unroll
    for (int r = 0; r < RPT; ++r) o[(size_t)r * NCH] = acc[r];
  }
  // ---- scale 1 (out index 0), taps g_wt[94..105], window u = t+25 ----
  {
    float acc[RPT];
    #pragma unroll
    for (int r = 0; r < RPT; ++r) acc[r] = 0.f;
    #pragma unroll
    for (int t = 0; t < 12; ++t) {
      const float wv = g_wt[94 + t];
      #pragma unroll
      for (int r = 0; r < RPT; ++r) acc[r] += wv * win[t + 25 + r];
    }
    float* o = outb + ((size_t)srow) * NCH + c;
    #pragma unroll
    for (int r = 0; r < RPT; ++r) o[(size_t)r * NCH] = acc[r];
  }
}

extern "C" void kernel_launch(void* const* d_in, const int* in_sizes, int n_in,
                              void* d_out, int out_size, void* d_ws, size_t ws_size,
                              hipStream_t stream) {
  (void)n_in; (void)out_size; (void)d_ws; (void)ws_size;
  const float* x = (const float*)d_in[0];
  float* out = (float*)d_out;
  const int B = in_sizes[0] / (S_LEN * NCH);   // 32

  hipLaunchKernelGGL(cwt_setup, dim3(1), dim3(64), 0, stream);
  dim3 grid(S_LEN / TILE_S, B);                // (32, 32) = 1024 blocks
  dim3 block(NCH, TY);                         // 512 threads
  hipLaunchKernelGGL(cwt_main, grid, block, 0, stream, x, out);
}

// Round 2
// 135.288 us; speedup vs baseline: 1.0633x; 1.0633x over previous
//
#include <hip/hip_runtime.h>
#include <math.h>

#define S_LEN  4096
#define NCH    64
#define TILE_S 128
#define RPT    16          // s-rows per thread
#define TY     8           // blockDim.y -> 512 threads = 8 waves
#define HALO_L 31
#define STAGE  (TILE_S + 61)   // 189 staged rows

// ---------------------------------------------------------------------------
// Single fused kernel.
//
// Weight construction (per block, redundant but ~free — overlapped with the
// global->LDS staging latency): replicates pywt/gaus1 filters.
//   numpy: x = linspace(-5,5,1024); step = x[1]-x[0];
//          psi = -2x e^{-x^2}/(pi/2)^{1/4}; int_psi = cumsum(psi)*step;
//          j = (arange(10a+1)/(a*step)).astype(int64); filt = f32(int_psi[j])
// Fused filter (conv + diff + trim folded): w_a[t] = -sqrt(a)*(k[t-1]-k[t]),
// t = 0..Lf (Lf = 10a), k[-1]=k[Lf+1]=0. The j index computation is identical
// fp64 ops so floor decisions match numpy bit-exactly (validated round 1).
// The fp64 cumsum uses a pairwise + shuffle-scan association; differs from
// numpy's serial cumsum only at ~1e-16 relative — invisible after f32 cast.
//
// Weight LDS layout (16B-aligned chunks): scale6 t=0..61 at [0..61],
// scale3 t=0..31 at [64..95], scale1 t=0..11 at [96..107].
//
// Main: out[b][si][s][c] = sum_t w[t] * x[b][s+off+t][c], zero-padded in s.
// Unified window base = s-31: w6 at u=t, w3 at u=t+15, w1 at u=t+25.
// ---------------------------------------------------------------------------
__global__ __launch_bounds__(512)
void cwt_fused(const float* __restrict__ x, float* __restrict__ out) {
  __shared__ __align__(16) float lds[STAGE * NCH];  // 48384 B
  __shared__ __align__(16) float wt[112];
  __shared__ float ipf[1024];                       // f32(int_psi)
  __shared__ double wsum[TY];

  const int c   = threadIdx.x;        // 0..63 (lane)
  const int ty  = threadIdx.y;        // 0..7 (wave)
  const int tid = ty * 64 + c;
  const int b   = blockIdx.y;
  const int s0  = blockIdx.x * TILE_S;
  const float* xb = x + (size_t)b * S_LEN * NCH;
  const int row0 = s0 - HALO_L;

  // ---- issue staging loads EARLY; fp64 weight math below hides the latency
  float4 stg[6];
  #pragma unroll
  for (int i = 0; i < 6; ++i) {
    const int idx = tid + i * 512;
    const int r = idx >> 4, q = idx & 15;
    const int row = row0 + r;
    float4 v = make_float4(0.f, 0.f, 0.f, 0.f);
    if (idx < STAGE * 16 && row >= 0 && row < S_LEN)
      v = *(const float4*)(xb + ((size_t)row * NCH + (q << 2)));
    stg[i] = v;
  }

  // ---- fp64 psi + pairwise cumsum (2 samples / thread, 1024 total) ----
  const double delta = 10.0 / 1023.0;
  const double step  = (-5.0 + delta) + 5.0;        // == numpy x[1]-x[0]
  const double cnorm = pow(3.141592653589793 * 0.5, 0.25);

  const int i0 = 2 * tid, i1 = 2 * tid + 1;
  const double x0 = (i0 == 1023) ? 5.0 : ((double)i0 * delta - 5.0);
  const double x1 = (i1 == 1023) ? 5.0 : ((double)i1 * delta - 5.0);
  const double p0 = (-2.0 * x0) * exp(-(x0 * x0)) / cnorm;
  const double p1 = (-2.0 * x1) * exp(-(x1 * x1)) / cnorm;
  const double s2 = p0 + p1;

  double inc = s2;                                   // wave-inclusive scan
  #pragma unroll
  for (int off = 1; off < 64; off <<= 1) {
    const double u = __shfl_up(inc, (unsigned)off, 64);
    if (c >= off) inc += u;
  }
  if (c == 63) wsum[ty] = inc;
  __syncthreads();

  double pre = 0.0;                                  // prefix of earlier waves
  #pragma unroll
  for (int k = 0; k < TY; ++k) if (k < ty) pre += wsum[k];
  const double excl = pre + (inc - s2);
  ipf[i0] = (float)((excl + p0) * step);
  ipf[i1] = (float)((excl + p0 + p1) * step);
  __syncthreads();

  // ---- gather filter taps (106 threads), fp64-exact floor indexing ----
  {
    int a = 0, ofs = 0, lf = 0, t = 0, live = 0;
    if (tid < 62)                   { a = 6; ofs = 0;  lf = 61; t = tid;      live = 1; }
    else if (tid >= 64 && tid < 96) { a = 3; ofs = 64; lf = 31; t = tid - 64; live = 1; }
    else if (tid >= 96 && tid < 108){ a = 1; ofs = 96; lf = 11; t = tid - 96; live = 1; }
    if (live) {
      const double denom = (double)a * step;
      const float  sqa   = (float)sqrt((double)a);
      float km1 = 0.f, kt = 0.f;
      if (t >= 1)      km1 = ipf[(int)(long)(((double)(t - 1)) / denom)];
      if (t <= lf - 1) kt  = ipf[(int)(long)(((double)t) / denom)];
      wt[ofs + t] = -sqa * (km1 - kt);
    }
  }

  // ---- commit staged rows to LDS ----
  #pragma unroll
  for (int i = 0; i < 6; ++i) {
    const int idx = tid + i * 512;
    if (idx < STAGE * 16)
      *(float4*)(&lds[(idx >> 4) * NCH + ((idx & 15) << 2)]) = stg[i];
  }
  __syncthreads();

  // ---- register window: rows base..base+76 for this thread's channel ----
  const int base = ty * RPT;
  float win[61 + RPT];
  #pragma unroll
  for (int u = 0; u < 61 + RPT; ++u) win[u] = lds[(base + u) * NCH + c];

  float* outb = out + (size_t)b * 3 * S_LEN * NCH;
  const int srow = s0 + base;
  const float4* wt4 = (const float4*)wt;

  // ---- scale 6 (out plane 2), taps wt[0..61], window u = t ----
  {
    float acc[RPT];
    #pragma unroll
    for (int r = 0; r < RPT; ++r) acc[r] = 0.f;
    #pragma unroll
    for (int t4 = 0; t4 < 15; ++t4) {
      const float4 w4 = wt4[t4];
      #pragma unroll
      for (int r = 0; r < RPT; ++r)
        acc[r] += w4.x * win[4 * t4 + r]     + w4.y * win[4 * t4 + 1 + r]
                + w4.z * win[4 * t4 + 2 + r] + w4.w * win[4 * t4 + 3 + r];
    }
    {
      const float2 w2 = *(const float2*)&wt[60];
      #pragma unroll
      for (int r = 0; r < RPT; ++r)
        acc[r] += w2.x * win[60 + r] + w2.y * win[61 + r];
    }
    float* o = outb + ((size_t)(2 * S_LEN + srow)) * NCH + c;
    #pragma unroll
    for (int r = 0; r < RPT; ++r) o[(size_t)r * NCH] = acc[r];
  }
  // ---- scale 3 (out plane 1), taps wt[64..95], window u = t+15 ----
  {
    float acc[RPT];
    #pragma unroll
    for (int r = 0; r < RPT; ++r) acc[r] = 0.f;
    #pragma unroll
    for (int t4 = 0; t4 < 8; ++t4) {
      const float4 w4 = wt4[16 + t4];
      #pragma unroll
      for (int r = 0; r < RPT; ++r)
        acc[r] += w4.x * win[4 * t4 + 15 + r] + w4.y * win[4 * t4 + 16 + r]
                + w4.z * win[4 * t4 + 17 + r] + w4.w * win[4 * t4 + 18 + r];
    }
    float* o = outb + ((size_t)(1 * S_LEN + srow)) * NCH + c;
    #pragma unroll
    for (int r = 0; r < RPT; ++r) o[(size_t)r * NCH] = acc[r];
  }
  // ---- scale 1 (out plane 0), taps wt[96..107], window u = t+25 ----
  {
    float acc[RPT];
    #pragma unroll
    for (int r = 0; r < RPT; ++r) acc[r] = 0.f;
    #pragma unroll
    for (int t4 = 0; t4 < 3; ++t4) {
      const float4 w4 = wt4[24 + t4];
      #pragma unroll
      for (int r = 0; r < RPT; ++r)
        acc[r] += w4.x * win[4 * t4 + 25 + r] + w4.y * win[4 * t4 + 26 + r]
                + w4.z * win[4 * t4 + 27 + r] + w4.w * win[4 * t4 + 28 + r];
    }
    float* o = outb + ((size_t)srow) * NCH + c;
    #pragma unroll
    for (int r = 0; r < RPT; ++r) o[(size_t)r * NCH] = acc[r];
  }
}

extern "C" void kernel_launch(void* const* d_in, const int* in_sizes, int n_in,
                              void* d_out, int out_size, void* d_ws, size_t ws_size,
                              hipStream_t stream) {
  (void)n_in; (void)out_size; (void)d_ws; (void)ws_size;
  const float* x = (const float*)d_in[0];
  float* out = (float*)d_out;
  const int B = in_sizes[0] / (S_LEN * NCH);   // 32

  dim3 grid(S_LEN / TILE_S, B);                // (32, 32) = 1024 blocks
  dim3 block(NCH, TY);                         // 512 threads = 8 waves
  hipLaunchKernelGGL(cwt_fused, grid, block, 0, stream, x, out);
}